// Round 5
// baseline (665.602 us; speedup 1.0000x reference)
//
#include <hip/hip_runtime.h>

#define NPATCH 1600
#define NHEAD 8
#define DHEAD 64
#define DMODEL 512
#define TBL 6241      // 79*79
#define QKVLD 1536
#define SROW 1608     // sfull row stride in floats (1608%32==8 -> 2-way banks, 16B aligned)

// ---------------------------------------------------------------------------
// GEMM: C[M][Nout] = A[M][512] @ W[Nout][512]^T
// ---------------------------------------------------------------------------
__global__ __launch_bounds__(256) void k_gemm_qkv(const float* __restrict__ x,
                                                  const float* __restrict__ w,
                                                  float* __restrict__ c,
                                                  int ldc) {
  __shared__ float As[16][68];
  __shared__ float Bs[16][68];
  const int t = threadIdx.x;
  const int m0 = blockIdx.x * 64;
  const int n0 = blockIdx.y * 64;
  const int tx = t & 15;
  const int ty = t >> 4;
  const int mr = t >> 2;
  const int k4 = (t & 3) * 4;
  float acc[4][4] = {};
  for (int k0 = 0; k0 < DMODEL; k0 += 16) {
    float4 a4 = *reinterpret_cast<const float4*>(x + (size_t)(m0 + mr) * DMODEL + k0 + k4);
    float4 b4 = *reinterpret_cast<const float4*>(w + (size_t)(n0 + mr) * DMODEL + k0 + k4);
    As[k4 + 0][mr] = a4.x; As[k4 + 1][mr] = a4.y; As[k4 + 2][mr] = a4.z; As[k4 + 3][mr] = a4.w;
    Bs[k4 + 0][mr] = b4.x; Bs[k4 + 1][mr] = b4.y; Bs[k4 + 2][mr] = b4.z; Bs[k4 + 3][mr] = b4.w;
    __syncthreads();
    const float4* As4 = reinterpret_cast<const float4*>(&As[0][0]);
    const float4* Bs4 = reinterpret_cast<const float4*>(&Bs[0][0]);
#pragma unroll
    for (int kk = 0; kk < 16; ++kk) {
      float4 av = As4[kk * 17 + tx];
      float4 bv = Bs4[kk * 17 + ty];
      acc[0][0] += av.x * bv.x; acc[0][1] += av.x * bv.y; acc[0][2] += av.x * bv.z; acc[0][3] += av.x * bv.w;
      acc[1][0] += av.y * bv.x; acc[1][1] += av.y * bv.y; acc[1][2] += av.y * bv.z; acc[1][3] += av.y * bv.w;
      acc[2][0] += av.z * bv.x; acc[2][1] += av.z * bv.y; acc[2][2] += av.z * bv.z; acc[2][3] += av.z * bv.w;
      acc[3][0] += av.w * bv.x; acc[3][1] += av.w * bv.y; acc[3][2] += av.w * bv.z; acc[3][3] += av.w * bv.w;
    }
    __syncthreads();
  }
#pragma unroll
  for (int i = 0; i < 4; ++i) {
    float4 o;
    o.x = acc[i][0]; o.y = acc[i][1]; o.z = acc[i][2]; o.w = acc[i][3];
    *reinterpret_cast<float4*>(c + (size_t)(m0 + tx * 4 + i) * ldc + n0 + ty * 4) = o;
  }
}

__global__ __launch_bounds__(256) void k_gemm_out(const float* __restrict__ a,
                                                  const float* __restrict__ w,
                                                  const float* __restrict__ bias,
                                                  const float* __restrict__ prob,
                                                  float* __restrict__ outp) {
  __shared__ float As[16][68];
  __shared__ float Bs[16][68];
  const int t = threadIdx.x;
  const int m0 = blockIdx.x * 64;
  const int n0 = blockIdx.y * 64;
  const int tx = t & 15;
  const int ty = t >> 4;
  const int mr = t >> 2;
  const int k4 = (t & 3) * 4;
  float acc[4][4] = {};
  for (int k0 = 0; k0 < DMODEL; k0 += 16) {
    float4 a4 = *reinterpret_cast<const float4*>(a + (size_t)(m0 + mr) * DMODEL + k0 + k4);
    float4 b4 = *reinterpret_cast<const float4*>(w + (size_t)(n0 + mr) * DMODEL + k0 + k4);
    As[k4 + 0][mr] = a4.x; As[k4 + 1][mr] = a4.y; As[k4 + 2][mr] = a4.z; As[k4 + 3][mr] = a4.w;
    Bs[k4 + 0][mr] = b4.x; Bs[k4 + 1][mr] = b4.y; Bs[k4 + 2][mr] = b4.z; Bs[k4 + 3][mr] = b4.w;
    __syncthreads();
    const float4* As4 = reinterpret_cast<const float4*>(&As[0][0]);
    const float4* Bs4 = reinterpret_cast<const float4*>(&Bs[0][0]);
#pragma unroll
    for (int kk = 0; kk < 16; ++kk) {
      float4 av = As4[kk * 17 + tx];
      float4 bv = Bs4[kk * 17 + ty];
      acc[0][0] += av.x * bv.x; acc[0][1] += av.x * bv.y; acc[0][2] += av.x * bv.z; acc[0][3] += av.x * bv.w;
      acc[1][0] += av.y * bv.x; acc[1][1] += av.y * bv.y; acc[1][2] += av.y * bv.z; acc[1][3] += av.y * bv.w;
      acc[2][0] += av.z * bv.x; acc[2][1] += av.z * bv.y; acc[2][2] += av.z * bv.z; acc[2][3] += av.z * bv.w;
      acc[3][0] += av.w * bv.x; acc[3][1] += av.w * bv.y; acc[3][2] += av.w * bv.z; acc[3][3] += av.w * bv.w;
    }
    __syncthreads();
  }
#pragma unroll
  for (int i = 0; i < 4; ++i) {
    const int row = m0 + tx * 4 + i;
    const bool sel = prob[row] < 0.9f;
    float4 o;
    o.x = acc[i][0] + bias[n0 + ty * 4 + 0];
    o.y = acc[i][1] + bias[n0 + ty * 4 + 1];
    o.z = acc[i][2] + bias[n0 + ty * 4 + 2];
    o.w = acc[i][3] + bias[n0 + ty * 4 + 3];
    if (!sel) { o.x = 0.f; o.y = 0.f; o.z = 0.f; o.w = 0.f; }
    *reinterpret_cast<float4*>(outp + (size_t)row * DMODEL + n0 + ty * 4) = o;
  }
}

__global__ void k_tprod(const float* __restrict__ t1, const float* __restrict__ t2,
                        float* __restrict__ tp) {
  const int o = blockIdx.x * 256 + threadIdx.x;
  if (o < NHEAD * TBL) {
    const int h = o / TBL;
    const int i = o - h * TBL;
    tp[o] = t1[i * NHEAD + h] * t2[i * NHEAD + h];
  }
}

// ---------------------------------------------------------------------------
// Fused attention. One block = (head, 8 query rows). 256 threads.
//  QK mapping: thread t -> key kq=t>>2 (4-lane broadcast of K reads),
//              row pair r0=(t&3)*2, r1=r0+1.
//  K stage: XOR-swizzled float4 layout ks4[c4*64 + (kr ^ (c4&7))] so that
//  BOTH the transposing write and the per-d4 read are bank-conflict-free.
//  T14: next chunk's global loads issued before compute of current chunk.
// ---------------------------------------------------------------------------
__global__ __launch_bounds__(256) void k_attn(const float* __restrict__ qkv,
                                              const float* __restrict__ tprod,
                                              const float* __restrict__ headsita,
                                              const float* __restrict__ w_thresh,
                                              float* __restrict__ attn0,
                                              float* __restrict__ out0) {
  __shared__ float sfull[8 * SROW];   // biased scores -> exp -> attn_p  (51.5 KB)
  __shared__ float ks[4096];          // K chunk, swizzled; reused as PV partials (16 KB)
  __shared__ float qs[8 * 68];        // Q rows, float4 row stride 17 (2.2 KB)
  const int t = threadIdx.x;
  const int h = blockIdx.y;
  const int n0 = blockIdx.x * 8;

  // --- stage Q ---
#pragma unroll
  for (int rep = 0; rep < 2; ++rep) {
    const int e = t + rep * 256;
    const int r = e >> 6, dd = e & 63;
    qs[r * 68 + dd] = qkv[(size_t)(n0 + r) * QKVLD + h * DHEAD + dd];
  }
  __syncthreads();

  // --- per-row threshold factor ---
  const int grp = t >> 5;
  const int lane = t & 31;
  float thr;
  {
    float p = qs[grp * 68 + lane] * w_thresh[lane] +
              qs[grp * 68 + 32 + lane] * w_thresh[32 + lane];
#pragma unroll
    for (int s = 16; s; s >>= 1) p += __shfl_xor(p, s, 32);
    thr = (1.0f / (1.0f + __expf(-p))) * 0.11920292202211755f;  // sigmoid(p)*sigmoid(-2)
  }
  const float hs = headsita[h];
  const float fac = 1.0f / (2.0f * hs * hs + 1e-6f);

  // --- QK^T over 25 chunks of 64 keys ---
  const int kq = t >> 2;                 // key lane 0..63
  const int r0 = (t & 3) * 2, r1 = r0 + 1;
  const int nA = n0 + r0, nB = n0 + r1;
  const int nhA = nA / 40, nwA = nA % 40;
  const int nhB = nB / 40, nwB = nB % 40;
  float4* ks4 = reinterpret_cast<float4*>(ks);
  const float4* qs4 = reinterpret_cast<const float4*>(qs);

  const int c4 = t & 15;                 // staging d-quad
  const int krb = t >> 4;                // staging key base 0..15
  const int swr = krb ^ (c4 & 7);        // swizzled low bits (still 0..15)
  const float* gK = qkv + DMODEL + h * DHEAD + c4 * 4;
  float4 st[4];
#pragma unroll
  for (int i = 0; i < 4; ++i)
    st[i] = *reinterpret_cast<const float4*>(gK + (size_t)(krb + 16 * i) * QKVLD);

  for (int mc = 0; mc < 25; ++mc) {
    __syncthreads();                      // previous chunk fully consumed
#pragma unroll
    for (int i = 0; i < 4; ++i)
      ks4[c4 * 64 + 16 * i + swr] = st[i];
    __syncthreads();                      // chunk ready
    if (mc < 24) {
      const int mb = (mc + 1) * 64;
#pragma unroll
      for (int i = 0; i < 4; ++i)
        st[i] = *reinterpret_cast<const float4*>(gK + (size_t)(mb + krb + 16 * i) * QKVLD);
    }

    float acc0 = 0.f, acc1 = 0.f;
#pragma unroll
    for (int d4 = 0; d4 < 16; ++d4) {
      const float4 kv = ks4[d4 * 64 + (kq ^ (d4 & 7))];
      const float4 qa = qs4[r0 * 17 + d4];
      const float4 qb = qs4[r1 * 17 + d4];
      acc0 = fmaf(kv.x, qa.x, acc0); acc0 = fmaf(kv.y, qa.y, acc0);
      acc0 = fmaf(kv.z, qa.z, acc0); acc0 = fmaf(kv.w, qa.w, acc0);
      acc1 = fmaf(kv.x, qb.x, acc1); acc1 = fmaf(kv.y, qb.y, acc1);
      acc1 = fmaf(kv.z, qb.z, acc1); acc1 = fmaf(kv.w, qb.w, acc1);
    }

    const int m = mc * 64 + kq;
    const int mh = m / 40, mw = m - mh * 40;
    {
      const float s0 = acc0 * 0.125f;
      attn0[(size_t)(h * NPATCH + nA) * NPATCH + m] = s0;
      const int dh = nhA - mh, dw = nwA - mw;
      const float fdh = (float)dh * 0.025f;
      const float fdwa = (float)dw * 0.025f;
      const float fdwb = (float)dw * (1.0f / 96.0f);
      const float dis = fdh * fdh + fdwa * fdwa + fdwb * fdwb;
      const float bias = tprod[h * TBL + (dh + 39) * 79 + (dw + 39)];
      sfull[r0 * SROW + m] = s0 + bias + 0.01f * __expf(-fac * dis);
    }
    {
      const float s0 = acc1 * 0.125f;
      attn0[(size_t)(h * NPATCH + nB) * NPATCH + m] = s0;
      const int dh = nhB - mh, dw = nwB - mw;
      const float fdh = (float)dh * 0.025f;
      const float fdwa = (float)dw * 0.025f;
      const float fdwb = (float)dw * (1.0f / 96.0f);
      const float dis = fdh * fdh + fdwa * fdwa + fdwb * fdwb;
      const float bias = tprod[h * TBL + (dh + 39) * 79 + (dw + 39)];
      sfull[r1 * SROW + m] = s0 + bias + 0.01f * __expf(-fac * dis);
    }
  }
  __syncthreads();

  // --- softmax + prune + renorm (32 lanes per row) ---
  {
    float* row = sfull + grp * SROW;
    float lmax = -3.4e38f;
    for (int i = lane; i < 1600; i += 32) lmax = fmaxf(lmax, row[i]);
#pragma unroll
    for (int s = 16; s; s >>= 1) lmax = fmaxf(lmax, __shfl_xor(lmax, s, 32));
    float lsum = 0.f, lmin = 3.4e38f;
    for (int i = lane; i < 1600; i += 32) {
      const float e = __expf(row[i] - lmax);
      row[i] = e;
      lsum += e;
      lmin = fminf(lmin, e);
    }
#pragma unroll
    for (int s = 16; s; s >>= 1) {
      lsum += __shfl_xor(lsum, s, 32);
      lmin = fminf(lmin, __shfl_xor(lmin, s, 32));
    }
    // attn > thresh  <=>  e > lmin + thr*(e_max(=1) - lmin)   (all /lsum)
    const float T = lmin + thr * (1.0f - lmin);
    float ld = 0.f;
    for (int i = lane; i < 1600; i += 32) {
      const float e = row[i];
      if (e > T) ld += e;
    }
#pragma unroll
    for (int s = 16; s; s >>= 1) ld += __shfl_xor(ld, s, 32);
    const float sc = 1.0f / (ld + 1e-6f * lsum);   // == 1/((deno+1e-6)*lsum) folded
    for (int i = lane; i < 1600; i += 32) {
      const float e = row[i];
      row[i] = (e > T) ? e * sc : 0.f;
    }
  }
  __syncthreads();

  // --- PV ---
  const int d = t & 63;
  const int g = t >> 6;
  float acc[8] = {0.f, 0.f, 0.f, 0.f, 0.f, 0.f, 0.f, 0.f};
  const float* vcol = qkv + 2 * DMODEL + h * DHEAD + d;
  const float4* sf4 = reinterpret_cast<const float4*>(sfull);
  for (int m = g * 400; m < g * 400 + 400; m += 4) {
    const float v0 = vcol[(size_t)(m + 0) * QKVLD];
    const float v1 = vcol[(size_t)(m + 1) * QKVLD];
    const float v2 = vcol[(size_t)(m + 2) * QKVLD];
    const float v3 = vcol[(size_t)(m + 3) * QKVLD];
#pragma unroll
    for (int r = 0; r < 8; ++r) {
      const float4 ap = sf4[r * 402 + (m >> 2)];
      acc[r] = fmaf(ap.x, v0, acc[r]);
      acc[r] = fmaf(ap.y, v1, acc[r]);
      acc[r] = fmaf(ap.z, v2, acc[r]);
      acc[r] = fmaf(ap.w, v3, acc[r]);
    }
  }
  float* part = ks;  // [4][8][64]
#pragma unroll
  for (int r = 0; r < 8; ++r) part[(g * 8 + r) * 64 + d] = acc[r];
  __syncthreads();
#pragma unroll
  for (int rep = 0; rep < 2; ++rep) {
    const int e = t + rep * 256;
    const int r = e >> 6, dd = e & 63;
    const float s = part[(0 + r) * 64 + dd] + part[(8 + r) * 64 + dd] +
                    part[(16 + r) * 64 + dd] + part[(24 + r) * 64 + dd];
    out0[(size_t)(n0 + r) * DMODEL + h * DHEAD + dd] = s;
  }
}

// row-softmax of raw dots0, in place
__global__ __launch_bounds__(256) void k_norm(float* __restrict__ attn0) {
  __shared__ float buf[1600];
  __shared__ float red[4];
  const int t = threadIdx.x;
  float* base = attn0 + (size_t)blockIdx.x * 1600;
  float lmax = -3.4e38f;
  for (int i = t; i < 1600; i += 256) {
    const float v = base[i];
    buf[i] = v;
    lmax = fmaxf(lmax, v);
  }
#pragma unroll
  for (int s = 32; s; s >>= 1) lmax = fmaxf(lmax, __shfl_xor(lmax, s, 64));
  if ((t & 63) == 0) red[t >> 6] = lmax;
  __syncthreads();
  const float M = fmaxf(fmaxf(red[0], red[1]), fmaxf(red[2], red[3]));
  float lsum = 0.f;
  for (int i = t; i < 1600; i += 256) {
    const float v = __expf(buf[i] - M);
    buf[i] = v;
    lsum += v;
  }
#pragma unroll
  for (int s = 32; s; s >>= 1) lsum += __shfl_xor(lsum, s, 64);
  __syncthreads();
  if ((t & 63) == 0) red[t >> 6] = lsum;
  __syncthreads();
  const float S = red[0] + red[1] + red[2] + red[3];
  const float inv = 1.0f / S;
  for (int i = t; i < 1600; i += 256) base[i] = buf[i] * inv;
}

extern "C" void kernel_launch(void* const* d_in, const int* in_sizes, int n_in,
                              void* d_out, int out_size, void* d_ws, size_t ws_size,
                              hipStream_t stream) {
  const float* x        = (const float*)d_in[0];
  const float* prob     = (const float*)d_in[1];
  const float* w_qkv    = (const float*)d_in[2];
  const float* table1   = (const float*)d_in[3];
  const float* table2   = (const float*)d_in[4];
  const float* headsita = (const float*)d_in[5];
  const float* w_thresh = (const float*)d_in[6];
  const float* w_out    = (const float*)d_in[7];
  const float* b_out    = (const float*)d_in[8];

  float* out   = (float*)d_out;
  float* attn0 = out + (size_t)NPATCH * DMODEL;

  float* qkvb  = (float*)d_ws;                          // [1600][1536]
  float* out0b = qkvb + (size_t)NPATCH * QKVLD;         // [1600][512]
  float* tpb   = out0b + (size_t)NPATCH * DMODEL;       // [8][6241]

  k_gemm_qkv<<<dim3(25, 24), 256, 0, stream>>>(x, w_qkv, qkvb, QKVLD);
  k_tprod<<<dim3((NHEAD * TBL + 255) / 256), 256, 0, stream>>>(table1, table2, tpb);
  k_attn<<<dim3(200, NHEAD), 256, 0, stream>>>(qkvb, tpb, headsita, w_thresh, attn0, out0b);
  k_norm<<<dim3(NHEAD * NPATCH), 256, 0, stream>>>(attn0);
  k_gemm_out<<<dim3(25, 8), 256, 0, stream>>>(out0b, w_out, b_out, prob, out);
}

// Round 6
// 644.228 us; speedup vs baseline: 1.0332x; 1.0332x over previous
//
#include <hip/hip_runtime.h>

#define NPATCH 1600
#define NHEAD 8
#define DHEAD 64
#define DMODEL 512
#define TBL 6241      // 79*79
#define QKVLD 1536
#define SROW 1608     // sfull row stride in floats (16B aligned; PV reads are wave-uniform broadcasts)

// ---------------------------------------------------------------------------
// GEMM: C[M][Nout] = A[M][512] @ W[Nout][512]^T
// ---------------------------------------------------------------------------
__global__ __launch_bounds__(256) void k_gemm_qkv(const float* __restrict__ x,
                                                  const float* __restrict__ w,
                                                  float* __restrict__ c,
                                                  int ldc) {
  __shared__ float As[16][68];
  __shared__ float Bs[16][68];
  const int t = threadIdx.x;
  const int m0 = blockIdx.x * 64;
  const int n0 = blockIdx.y * 64;
  const int tx = t & 15;
  const int ty = t >> 4;
  const int mr = t >> 2;
  const int k4 = (t & 3) * 4;
  float acc[4][4] = {};
  for (int k0 = 0; k0 < DMODEL; k0 += 16) {
    float4 a4 = *reinterpret_cast<const float4*>(x + (size_t)(m0 + mr) * DMODEL + k0 + k4);
    float4 b4 = *reinterpret_cast<const float4*>(w + (size_t)(n0 + mr) * DMODEL + k0 + k4);
    As[k4 + 0][mr] = a4.x; As[k4 + 1][mr] = a4.y; As[k4 + 2][mr] = a4.z; As[k4 + 3][mr] = a4.w;
    Bs[k4 + 0][mr] = b4.x; Bs[k4 + 1][mr] = b4.y; Bs[k4 + 2][mr] = b4.z; Bs[k4 + 3][mr] = b4.w;
    __syncthreads();
    const float4* As4 = reinterpret_cast<const float4*>(&As[0][0]);
    const float4* Bs4 = reinterpret_cast<const float4*>(&Bs[0][0]);
#pragma unroll
    for (int kk = 0; kk < 16; ++kk) {
      float4 av = As4[kk * 17 + tx];
      float4 bv = Bs4[kk * 17 + ty];
      acc[0][0] += av.x * bv.x; acc[0][1] += av.x * bv.y; acc[0][2] += av.x * bv.z; acc[0][3] += av.x * bv.w;
      acc[1][0] += av.y * bv.x; acc[1][1] += av.y * bv.y; acc[1][2] += av.y * bv.z; acc[1][3] += av.y * bv.w;
      acc[2][0] += av.z * bv.x; acc[2][1] += av.z * bv.y; acc[2][2] += av.z * bv.z; acc[2][3] += av.z * bv.w;
      acc[3][0] += av.w * bv.x; acc[3][1] += av.w * bv.y; acc[3][2] += av.w * bv.z; acc[3][3] += av.w * bv.w;
    }
    __syncthreads();
  }
#pragma unroll
  for (int i = 0; i < 4; ++i) {
    float4 o;
    o.x = acc[i][0]; o.y = acc[i][1]; o.z = acc[i][2]; o.w = acc[i][3];
    *reinterpret_cast<float4*>(c + (size_t)(m0 + tx * 4 + i) * ldc + n0 + ty * 4) = o;
  }
}

__global__ __launch_bounds__(256) void k_gemm_out(const float* __restrict__ a,
                                                  const float* __restrict__ w,
                                                  const float* __restrict__ bias,
                                                  const float* __restrict__ prob,
                                                  float* __restrict__ outp) {
  __shared__ float As[16][68];
  __shared__ float Bs[16][68];
  const int t = threadIdx.x;
  const int m0 = blockIdx.x * 64;
  const int n0 = blockIdx.y * 64;
  const int tx = t & 15;
  const int ty = t >> 4;
  const int mr = t >> 2;
  const int k4 = (t & 3) * 4;
  float acc[4][4] = {};
  for (int k0 = 0; k0 < DMODEL; k0 += 16) {
    float4 a4 = *reinterpret_cast<const float4*>(a + (size_t)(m0 + mr) * DMODEL + k0 + k4);
    float4 b4 = *reinterpret_cast<const float4*>(w + (size_t)(n0 + mr) * DMODEL + k0 + k4);
    As[k4 + 0][mr] = a4.x; As[k4 + 1][mr] = a4.y; As[k4 + 2][mr] = a4.z; As[k4 + 3][mr] = a4.w;
    Bs[k4 + 0][mr] = b4.x; Bs[k4 + 1][mr] = b4.y; Bs[k4 + 2][mr] = b4.z; Bs[k4 + 3][mr] = b4.w;
    __syncthreads();
    const float4* As4 = reinterpret_cast<const float4*>(&As[0][0]);
    const float4* Bs4 = reinterpret_cast<const float4*>(&Bs[0][0]);
#pragma unroll
    for (int kk = 0; kk < 16; ++kk) {
      float4 av = As4[kk * 17 + tx];
      float4 bv = Bs4[kk * 17 + ty];
      acc[0][0] += av.x * bv.x; acc[0][1] += av.x * bv.y; acc[0][2] += av.x * bv.z; acc[0][3] += av.x * bv.w;
      acc[1][0] += av.y * bv.x; acc[1][1] += av.y * bv.y; acc[1][2] += av.y * bv.z; acc[1][3] += av.y * bv.w;
      acc[2][0] += av.z * bv.x; acc[2][1] += av.z * bv.y; acc[2][2] += av.z * bv.z; acc[2][3] += av.z * bv.w;
      acc[3][0] += av.w * bv.x; acc[3][1] += av.w * bv.y; acc[3][2] += av.w * bv.z; acc[3][3] += av.w * bv.w;
    }
    __syncthreads();
  }
#pragma unroll
  for (int i = 0; i < 4; ++i) {
    const int row = m0 + tx * 4 + i;
    const bool sel = prob[row] < 0.9f;
    float4 o;
    o.x = acc[i][0] + bias[n0 + ty * 4 + 0];
    o.y = acc[i][1] + bias[n0 + ty * 4 + 1];
    o.z = acc[i][2] + bias[n0 + ty * 4 + 2];
    o.w = acc[i][3] + bias[n0 + ty * 4 + 3];
    if (!sel) { o.x = 0.f; o.y = 0.f; o.z = 0.f; o.w = 0.f; }
    *reinterpret_cast<float4*>(outp + (size_t)row * DMODEL + n0 + ty * 4) = o;
  }
}

__global__ void k_tprod(const float* __restrict__ t1, const float* __restrict__ t2,
                        float* __restrict__ tp) {
  const int o = blockIdx.x * 256 + threadIdx.x;
  if (o < NHEAD * TBL) {
    const int h = o / TBL;
    const int i = o - h * TBL;
    tp[o] = t1[i * NHEAD + h] * t2[i * NHEAD + h];
  }
}

// ---------------------------------------------------------------------------
// Fused attention + attn0 softmax. One block = (head, 8 query rows), 256 thr.
//  QK mapping (round-0 style, coalesced global writes): m_lane = t&63 is the
//  key index; wave wv owns rows rA=2wv, rB=2wv+1 entirely.
//  K stage XOR-swizzle (round-1, kept): write ks4[c4*64+16i+(krb^(c4&7))],
//  read ks4[d4*64+(m_lane^(d4&7))] — same involution both sides; write
//  conflict-free, read 2-way (free).
//  attn0 softmax fused: raw scores transported via attn0 (same-lane RAW,
//  L1/L2-hot), re-read into unrolled va[25], wave-reduced, rewritten.
// ---------------------------------------------------------------------------
__global__ __launch_bounds__(256) void k_attn(const float* __restrict__ qkv,
                                              const float* __restrict__ tprod,
                                              const float* __restrict__ headsita,
                                              const float* __restrict__ w_thresh,
                                              float* __restrict__ attn0,
                                              float* __restrict__ out0) {
  __shared__ float sfull[8 * SROW];   // biased scores -> exp -> attn_p (51.5 KB)
  __shared__ float ks[4096];          // K chunk, swizzled; reused as PV partials (16 KB)
  __shared__ float qs[8 * 68];        // Q rows, float4 row stride 17 (2.2 KB)
  const int t = threadIdx.x;
  const int h = blockIdx.y;
  const int n0 = blockIdx.x * 8;

  // --- stage Q ---
#pragma unroll
  for (int rep = 0; rep < 2; ++rep) {
    const int e = t + rep * 256;
    const int r = e >> 6, dd = e & 63;
    qs[r * 68 + dd] = qkv[(size_t)(n0 + r) * QKVLD + h * DHEAD + dd];
  }
  __syncthreads();

  // --- per-row threshold factor ---
  const int grp = t >> 5;
  const int lane = t & 31;
  float thr;
  {
    float p = qs[grp * 68 + lane] * w_thresh[lane] +
              qs[grp * 68 + 32 + lane] * w_thresh[32 + lane];
#pragma unroll
    for (int s = 16; s; s >>= 1) p += __shfl_xor(p, s, 32);
    thr = (1.0f / (1.0f + __expf(-p))) * 0.11920292202211755f;  // sigmoid(p)*sigmoid(-2)
  }
  const float hs = headsita[h];
  const float fac = 1.0f / (2.0f * hs * hs + 1e-6f);

  // --- QK^T over 25 chunks of 64 keys ---
  const int m_lane = t & 63;             // key lane, full wave -> coalesced stores
  const int wv = t >> 6;
  const int rA = wv * 2, rB = rA + 1;
  const int nA = n0 + rA, nB = n0 + rB;
  const int nhA = nA / 40, nwA = nA % 40;
  const int nhB = nB / 40, nwB = nB % 40;
  float4* ks4 = reinterpret_cast<float4*>(ks);
  const float4* qs4 = reinterpret_cast<const float4*>(qs);

  const int c4 = t & 15;                 // staging d-quad
  const int krb = t >> 4;                // staging key base 0..15
  const int swr = krb ^ (c4 & 7);        // swizzled low 4 bits (still 0..15)
  const float* gK = qkv + DMODEL + h * DHEAD + c4 * 4;
  float4 st[4];
#pragma unroll
  for (int i = 0; i < 4; ++i)
    st[i] = *reinterpret_cast<const float4*>(gK + (size_t)(krb + 16 * i) * QKVLD);

  for (int mc = 0; mc < 25; ++mc) {
    __syncthreads();                      // previous chunk fully consumed
#pragma unroll
    for (int i = 0; i < 4; ++i)
      ks4[c4 * 64 + 16 * i + swr] = st[i];
    __syncthreads();                      // chunk ready
    if (mc < 24) {
      const int mb = (mc + 1) * 64;
#pragma unroll
      for (int i = 0; i < 4; ++i)
        st[i] = *reinterpret_cast<const float4*>(gK + (size_t)(mb + krb + 16 * i) * QKVLD);
    }

    float acc0 = 0.f, acc1 = 0.f;
#pragma unroll
    for (int d4 = 0; d4 < 16; ++d4) {
      const float4 kv = ks4[d4 * 64 + (m_lane ^ (d4 & 7))];
      const float4 qa = qs4[rA * 17 + d4];
      const float4 qb = qs4[rB * 17 + d4];
      acc0 = fmaf(kv.x, qa.x, acc0); acc0 = fmaf(kv.y, qa.y, acc0);
      acc0 = fmaf(kv.z, qa.z, acc0); acc0 = fmaf(kv.w, qa.w, acc0);
      acc1 = fmaf(kv.x, qb.x, acc1); acc1 = fmaf(kv.y, qb.y, acc1);
      acc1 = fmaf(kv.z, qb.z, acc1); acc1 = fmaf(kv.w, qb.w, acc1);
    }

    const int m = mc * 64 + m_lane;
    const int mh = m / 40, mw = m - mh * 40;
    {
      const float s0 = acc0 * 0.125f;
      attn0[(size_t)(h * NPATCH + nA) * NPATCH + m] = s0;   // raw, coalesced 256B/wave
      const int dh = nhA - mh, dw = nwA - mw;
      const float fdh = (float)dh * 0.025f;
      const float fdwa = (float)dw * 0.025f;
      const float fdwb = (float)dw * (1.0f / 96.0f);
      const float dis = fdh * fdh + fdwa * fdwa + fdwb * fdwb;
      const float bias = tprod[h * TBL + (dh + 39) * 79 + (dw + 39)];
      sfull[rA * SROW + m] = s0 + bias + 0.01f * __expf(-fac * dis);
    }
    {
      const float s0 = acc1 * 0.125f;
      attn0[(size_t)(h * NPATCH + nB) * NPATCH + m] = s0;
      const int dh = nhB - mh, dw = nwB - mw;
      const float fdh = (float)dh * 0.025f;
      const float fdwa = (float)dw * 0.025f;
      const float fdwb = (float)dw * (1.0f / 96.0f);
      const float dis = fdh * fdh + fdwa * fdwa + fdwb * fdwb;
      const float bias = tprod[h * TBL + (dh + 39) * 79 + (dw + 39)];
      sfull[rB * SROW + m] = s0 + bias + 0.01f * __expf(-fac * dis);
    }
  }

  // --- fused softmax of raw dots0 -> attn0 (wave-local; same-lane RAW reads,
  //     L1/L2-hot; fully unrolled register array, no scratch) ---
  {
    float* prow = attn0 + (size_t)(h * NPATCH + nA) * NPATCH;
    float va[25];
#pragma unroll
    for (int j = 0; j < 25; ++j) va[j] = prow[j * 64 + m_lane];
    float mx = -3.4e38f;
#pragma unroll
    for (int j = 0; j < 25; ++j) mx = fmaxf(mx, va[j]);
#pragma unroll
    for (int s = 32; s; s >>= 1) mx = fmaxf(mx, __shfl_xor(mx, s, 64));
    float sm = 0.f;
#pragma unroll
    for (int j = 0; j < 25; ++j) { va[j] = __expf(va[j] - mx); sm += va[j]; }
#pragma unroll
    for (int s = 32; s; s >>= 1) sm += __shfl_xor(sm, s, 64);
    const float inv = 1.0f / sm;
#pragma unroll
    for (int j = 0; j < 25; ++j) prow[j * 64 + m_lane] = va[j] * inv;
  }
  {
    float* prow = attn0 + (size_t)(h * NPATCH + nB) * NPATCH;
    float va[25];
#pragma unroll
    for (int j = 0; j < 25; ++j) va[j] = prow[j * 64 + m_lane];
    float mx = -3.4e38f;
#pragma unroll
    for (int j = 0; j < 25; ++j) mx = fmaxf(mx, va[j]);
#pragma unroll
    for (int s = 32; s; s >>= 1) mx = fmaxf(mx, __shfl_xor(mx, s, 64));
    float sm = 0.f;
#pragma unroll
    for (int j = 0; j < 25; ++j) { va[j] = __expf(va[j] - mx); sm += va[j]; }
#pragma unroll
    for (int s = 32; s; s >>= 1) sm += __shfl_xor(sm, s, 64);
    const float inv = 1.0f / sm;
#pragma unroll
    for (int j = 0; j < 25; ++j) prow[j * 64 + m_lane] = va[j] * inv;
  }
  __syncthreads();

  // --- softmax + prune + renorm on biased scores (32 lanes per row) ---
  {
    float* row = sfull + grp * SROW;
    float lmax = -3.4e38f;
    for (int i = lane; i < 1600; i += 32) lmax = fmaxf(lmax, row[i]);
#pragma unroll
    for (int s = 16; s; s >>= 1) lmax = fmaxf(lmax, __shfl_xor(lmax, s, 32));
    float lsum = 0.f, lmin = 3.4e38f;
    for (int i = lane; i < 1600; i += 32) {
      const float e = __expf(row[i] - lmax);
      row[i] = e;
      lsum += e;
      lmin = fminf(lmin, e);
    }
#pragma unroll
    for (int s = 16; s; s >>= 1) {
      lsum += __shfl_xor(lsum, s, 32);
      lmin = fminf(lmin, __shfl_xor(lmin, s, 32));
    }
    // attn > thresh  <=>  e > lmin + thr*(1 - lmin)   (everything /lsum)
    const float T = lmin + thr * (1.0f - lmin);
    float ld = 0.f;
    for (int i = lane; i < 1600; i += 32) {
      const float e = row[i];
      if (e > T) ld += e;
    }
#pragma unroll
    for (int s = 16; s; s >>= 1) ld += __shfl_xor(ld, s, 32);
    const float sc = 1.0f / (ld + 1e-6f * lsum);   // 1/((deno+1e-6)) in exp units
    for (int i = lane; i < 1600; i += 32) {
      const float e = row[i];
      row[i] = (e > T) ? e * sc : 0.f;
    }
  }
  __syncthreads();

  // --- PV ---
  const int d = t & 63;
  const int g = t >> 6;
  float acc[8] = {0.f, 0.f, 0.f, 0.f, 0.f, 0.f, 0.f, 0.f};
  const float* vcol = qkv + 2 * DMODEL + h * DHEAD + d;
  const float4* sf4 = reinterpret_cast<const float4*>(sfull);
  for (int m = g * 400; m < g * 400 + 400; m += 4) {
    const float v0 = vcol[(size_t)(m + 0) * QKVLD];
    const float v1 = vcol[(size_t)(m + 1) * QKVLD];
    const float v2 = vcol[(size_t)(m + 2) * QKVLD];
    const float v3 = vcol[(size_t)(m + 3) * QKVLD];
#pragma unroll
    for (int r = 0; r < 8; ++r) {
      const float4 ap = sf4[r * 402 + (m >> 2)];
      acc[r] = fmaf(ap.x, v0, acc[r]);
      acc[r] = fmaf(ap.y, v1, acc[r]);
      acc[r] = fmaf(ap.z, v2, acc[r]);
      acc[r] = fmaf(ap.w, v3, acc[r]);
    }
  }
  float* part = ks;  // [4][8][64]
#pragma unroll
  for (int r = 0; r < 8; ++r) part[(g * 8 + r) * 64 + d] = acc[r];
  __syncthreads();
#pragma unroll
  for (int rep = 0; rep < 2; ++rep) {
    const int e = t + rep * 256;
    const int r = e >> 6, dd = e & 63;
    const float s = part[(0 + r) * 64 + dd] + part[(8 + r) * 64 + dd] +
                    part[(16 + r) * 64 + dd] + part[(24 + r) * 64 + dd];
    out0[(size_t)(n0 + r) * DMODEL + h * DHEAD + dd] = s;
  }
}

extern "C" void kernel_launch(void* const* d_in, const int* in_sizes, int n_in,
                              void* d_out, int out_size, void* d_ws, size_t ws_size,
                              hipStream_t stream) {
  const float* x        = (const float*)d_in[0];
  const float* prob     = (const float*)d_in[1];
  const float* w_qkv    = (const float*)d_in[2];
  const float* table1   = (const float*)d_in[3];
  const float* table2   = (const float*)d_in[4];
  const float* headsita = (const float*)d_in[5];
  const float* w_thresh = (const float*)d_in[6];
  const float* w_out    = (const float*)d_in[7];
  const float* b_out    = (const float*)d_in[8];

  float* out   = (float*)d_out;
  float* attn0 = out + (size_t)NPATCH * DMODEL;

  float* qkvb  = (float*)d_ws;                          // [1600][1536]
  float* out0b = qkvb + (size_t)NPATCH * QKVLD;         // [1600][512]
  float* tpb   = out0b + (size_t)NPATCH * DMODEL;       // [8][6241]

  k_gemm_qkv<<<dim3(25, 24), 256, 0, stream>>>(x, w_qkv, qkvb, QKVLD);
  k_tprod<<<dim3((NHEAD * TBL + 255) / 256), 256, 0, stream>>>(table1, table2, tpb);
  k_attn<<<dim3(200, NHEAD), 256, 0, stream>>>(qkvb, tpb, headsita, w_thresh, attn0, out0b);
  k_gemm_out<<<dim3(25, 8), 256, 0, stream>>>(out0b, w_out, b_out, prob, out);
}

// Round 7
// 422.752 us; speedup vs baseline: 1.5745x; 1.5239x over previous
//
#include <hip/hip_runtime.h>

#define NPATCH 1600
#define NHEAD 8
#define DHEAD 64
#define DMODEL 512
#define TBL 6241      // 79*79
#define QKVLD 1536
#define SROW 1608     // sfull row stride (floats): 1608%32==8 -> 2-way banks, 16B aligned
#define KSLD 65       // padded K-tile row stride in float4 (write 2-way, read linear)

// ---------------------------------------------------------------------------
// GEMM: C[M][Nout] = A[M][512] @ W[Nout][512]^T
// ---------------------------------------------------------------------------
__global__ __launch_bounds__(256) void k_gemm_qkv(const float* __restrict__ x,
                                                  const float* __restrict__ w,
                                                  float* __restrict__ c,
                                                  int ldc) {
  __shared__ float As[16][68];
  __shared__ float Bs[16][68];
  const int t = threadIdx.x;
  const int m0 = blockIdx.x * 64;
  const int n0 = blockIdx.y * 64;
  const int tx = t & 15;
  const int ty = t >> 4;
  const int mr = t >> 2;
  const int k4 = (t & 3) * 4;
  float acc[4][4] = {};
  for (int k0 = 0; k0 < DMODEL; k0 += 16) {
    float4 a4 = *reinterpret_cast<const float4*>(x + (size_t)(m0 + mr) * DMODEL + k0 + k4);
    float4 b4 = *reinterpret_cast<const float4*>(w + (size_t)(n0 + mr) * DMODEL + k0 + k4);
    As[k4 + 0][mr] = a4.x; As[k4 + 1][mr] = a4.y; As[k4 + 2][mr] = a4.z; As[k4 + 3][mr] = a4.w;
    Bs[k4 + 0][mr] = b4.x; Bs[k4 + 1][mr] = b4.y; Bs[k4 + 2][mr] = b4.z; Bs[k4 + 3][mr] = b4.w;
    __syncthreads();
    const float4* As4 = reinterpret_cast<const float4*>(&As[0][0]);
    const float4* Bs4 = reinterpret_cast<const float4*>(&Bs[0][0]);
#pragma unroll
    for (int kk = 0; kk < 16; ++kk) {
      float4 av = As4[kk * 17 + tx];
      float4 bv = Bs4[kk * 17 + ty];
      acc[0][0] += av.x * bv.x; acc[0][1] += av.x * bv.y; acc[0][2] += av.x * bv.z; acc[0][3] += av.x * bv.w;
      acc[1][0] += av.y * bv.x; acc[1][1] += av.y * bv.y; acc[1][2] += av.y * bv.z; acc[1][3] += av.y * bv.w;
      acc[2][0] += av.z * bv.x; acc[2][1] += av.z * bv.y; acc[2][2] += av.z * bv.z; acc[2][3] += av.z * bv.w;
      acc[3][0] += av.w * bv.x; acc[3][1] += av.w * bv.y; acc[3][2] += av.w * bv.z; acc[3][3] += av.w * bv.w;
    }
    __syncthreads();
  }
#pragma unroll
  for (int i = 0; i < 4; ++i) {
    float4 o;
    o.x = acc[i][0]; o.y = acc[i][1]; o.z = acc[i][2]; o.w = acc[i][3];
    *reinterpret_cast<float4*>(c + (size_t)(m0 + tx * 4 + i) * ldc + n0 + ty * 4) = o;
  }
}

__global__ __launch_bounds__(256) void k_gemm_out(const float* __restrict__ a,
                                                  const float* __restrict__ w,
                                                  const float* __restrict__ bias,
                                                  const float* __restrict__ prob,
                                                  float* __restrict__ outp) {
  __shared__ float As[16][68];
  __shared__ float Bs[16][68];
  const int t = threadIdx.x;
  const int m0 = blockIdx.x * 64;
  const int n0 = blockIdx.y * 64;
  const int tx = t & 15;
  const int ty = t >> 4;
  const int mr = t >> 2;
  const int k4 = (t & 3) * 4;
  float acc[4][4] = {};
  for (int k0 = 0; k0 < DMODEL; k0 += 16) {
    float4 a4 = *reinterpret_cast<const float4*>(a + (size_t)(m0 + mr) * DMODEL + k0 + k4);
    float4 b4 = *reinterpret_cast<const float4*>(w + (size_t)(n0 + mr) * DMODEL + k0 + k4);
    As[k4 + 0][mr] = a4.x; As[k4 + 1][mr] = a4.y; As[k4 + 2][mr] = a4.z; As[k4 + 3][mr] = a4.w;
    Bs[k4 + 0][mr] = b4.x; Bs[k4 + 1][mr] = b4.y; Bs[k4 + 2][mr] = b4.z; Bs[k4 + 3][mr] = b4.w;
    __syncthreads();
    const float4* As4 = reinterpret_cast<const float4*>(&As[0][0]);
    const float4* Bs4 = reinterpret_cast<const float4*>(&Bs[0][0]);
#pragma unroll
    for (int kk = 0; kk < 16; ++kk) {
      float4 av = As4[kk * 17 + tx];
      float4 bv = Bs4[kk * 17 + ty];
      acc[0][0] += av.x * bv.x; acc[0][1] += av.x * bv.y; acc[0][2] += av.x * bv.z; acc[0][3] += av.x * bv.w;
      acc[1][0] += av.y * bv.x; acc[1][1] += av.y * bv.y; acc[1][2] += av.y * bv.z; acc[1][3] += av.y * bv.w;
      acc[2][0] += av.z * bv.x; acc[2][1] += av.z * bv.y; acc[2][2] += av.z * bv.z; acc[2][3] += av.z * bv.w;
      acc[3][0] += av.w * bv.x; acc[3][1] += av.w * bv.y; acc[3][2] += av.w * bv.z; acc[3][3] += av.w * bv.w;
    }
    __syncthreads();
  }
#pragma unroll
  for (int i = 0; i < 4; ++i) {
    const int row = m0 + tx * 4 + i;
    const bool sel = prob[row] < 0.9f;
    float4 o;
    o.x = acc[i][0] + bias[n0 + ty * 4 + 0];
    o.y = acc[i][1] + bias[n0 + ty * 4 + 1];
    o.z = acc[i][2] + bias[n0 + ty * 4 + 2];
    o.w = acc[i][3] + bias[n0 + ty * 4 + 3];
    if (!sel) { o.x = 0.f; o.y = 0.f; o.z = 0.f; o.w = 0.f; }
    *reinterpret_cast<float4*>(outp + (size_t)row * DMODEL + n0 + ty * 4) = o;
  }
}

__global__ void k_tprod(const float* __restrict__ t1, const float* __restrict__ t2,
                        float* __restrict__ tp) {
  const int o = blockIdx.x * 256 + threadIdx.x;
  if (o < NHEAD * TBL) {
    const int h = o / TBL;
    const int i = o - h * TBL;
    tp[o] = t1[i * NHEAD + h] * t2[i * NHEAD + h];
  }
}

// ---------------------------------------------------------------------------
// Fused attention. One block = (head, 8 query rows), 256 threads, 4 waves.
// Wave wv owns rows rA=2wv, rB=2wv+1; lane m_lane = t&63 indexes keys.
//  - K tile in LDS, PADDED layout [16][65] float4: transposing write is 2-way
//    (free), read ks4[d4*65+m_lane] is linear (offset-immediate folding, no
//    address VALU). Round-0 pipeline (load->write->barrier->compute).
//  - Chunk loop stores only RAW s0 to sfull; bias/pos moved out of the loop.
//  - attn0 = softmax(raw) computed per-wave from registers va[25], written
//    ONCE (coalesced), never re-read. No separate k_norm kernel.
//  - Prune softmax in registers vb[25] = raw + bias + 0.01*pos (recomputed
//    once per element, identical fp expression); attn_p written to sfull
//    for the PV pass.
// ---------------------------------------------------------------------------
__global__ __launch_bounds__(256) void k_attn(const float* __restrict__ qkv,
                                              const float* __restrict__ tprod,
                                              const float* __restrict__ headsita,
                                              const float* __restrict__ w_thresh,
                                              float* __restrict__ attn0,
                                              float* __restrict__ out0) {
  __shared__ float sfull[8 * SROW];     // raw scores -> attn_p (51.5 KB)
  __shared__ float ks[16 * KSLD * 4];   // padded K chunk; reused as PV partials (16.6 KB)
  __shared__ float qs[8 * 68];          // Q rows, float4 row stride 17 (2.2 KB)
  const int t = threadIdx.x;
  const int h = blockIdx.y;
  const int n0 = blockIdx.x * 8;

  // --- stage Q ---
#pragma unroll
  for (int rep = 0; rep < 2; ++rep) {
    const int e = t + rep * 256;
    const int r = e >> 6, dd = e & 63;
    qs[r * 68 + dd] = qkv[(size_t)(n0 + r) * QKVLD + h * DHEAD + dd];
  }
  __syncthreads();

  const int m_lane = t & 63;
  const int wv = t >> 6;
  const int rA = wv * 2, rB = rA + 1;
  const int nA = n0 + rA, nB = n0 + rB;

  // --- per-row threshold factor (64-lane reduce) ---
  float thrA, thrB;
  {
    const float wt = w_thresh[m_lane];
    float pA = qs[rA * 68 + m_lane] * wt;
    float pB = qs[rB * 68 + m_lane] * wt;
#pragma unroll
    for (int s = 32; s; s >>= 1) {
      pA += __shfl_xor(pA, s, 64);
      pB += __shfl_xor(pB, s, 64);
    }
    thrA = (1.0f / (1.0f + __expf(-pA))) * 0.11920292202211755f;  // sigmoid(p)*sigmoid(-2)
    thrB = (1.0f / (1.0f + __expf(-pB))) * 0.11920292202211755f;
  }
  const float hs = headsita[h];
  const float fac = 1.0f / (2.0f * hs * hs + 1e-6f);

  // --- QK^T over 25 chunks of 64 keys: raw scores only ---
  float4* ks4 = reinterpret_cast<float4*>(ks);
  const float4* qs4 = reinterpret_cast<const float4*>(qs);
  const int c4 = t & 15;                 // staging d-quad
  const int krb = t >> 4;                // staging key 0..15
  const float* gK = qkv + DMODEL + h * DHEAD + c4 * 4;

  for (int mc = 0; mc < 25; ++mc) {
    const int mb = mc * 64;
    float4 s0v = *reinterpret_cast<const float4*>(gK + (size_t)(mb + krb) * QKVLD);
    float4 s1v = *reinterpret_cast<const float4*>(gK + (size_t)(mb + krb + 16) * QKVLD);
    float4 s2v = *reinterpret_cast<const float4*>(gK + (size_t)(mb + krb + 32) * QKVLD);
    float4 s3v = *reinterpret_cast<const float4*>(gK + (size_t)(mb + krb + 48) * QKVLD);
    __syncthreads();                      // previous chunk fully consumed
    ks4[c4 * KSLD + krb]      = s0v;
    ks4[c4 * KSLD + krb + 16] = s1v;
    ks4[c4 * KSLD + krb + 32] = s2v;
    ks4[c4 * KSLD + krb + 48] = s3v;
    __syncthreads();                      // chunk ready

    float acc0 = 0.f, acc1 = 0.f;
#pragma unroll
    for (int d4 = 0; d4 < 16; ++d4) {
      const float4 kv = ks4[d4 * KSLD + m_lane];
      const float4 qa = qs4[rA * 17 + d4];
      const float4 qb = qs4[rB * 17 + d4];
      acc0 = fmaf(kv.x, qa.x, acc0); acc0 = fmaf(kv.y, qa.y, acc0);
      acc0 = fmaf(kv.z, qa.z, acc0); acc0 = fmaf(kv.w, qa.w, acc0);
      acc1 = fmaf(kv.x, qb.x, acc1); acc1 = fmaf(kv.y, qb.y, acc1);
      acc1 = fmaf(kv.z, qb.z, acc1); acc1 = fmaf(kv.w, qb.w, acc1);
    }
    sfull[rA * SROW + mb + m_lane] = acc0 * 0.125f;
    sfull[rB * SROW + mb + m_lane] = acc1 * 0.125f;
  }
  // rows rA/rB below are read/written only by their owning wave -> no barrier.

  // --- attn0 = softmax(raw), written once, coalesced ---
#pragma unroll
  for (int rr = 0; rr < 2; ++rr) {
    const int r = rA + rr;
    const float* srow = sfull + r * SROW;
    float va[25];
#pragma unroll
    for (int j = 0; j < 25; ++j) va[j] = srow[j * 64 + m_lane];
    float mx = -3.4e38f;
#pragma unroll
    for (int j = 0; j < 25; ++j) mx = fmaxf(mx, va[j]);
#pragma unroll
    for (int s = 32; s; s >>= 1) mx = fmaxf(mx, __shfl_xor(mx, s, 64));
    float sm = 0.f;
#pragma unroll
    for (int j = 0; j < 25; ++j) { va[j] = __expf(va[j] - mx); sm += va[j]; }
#pragma unroll
    for (int s = 32; s; s >>= 1) sm += __shfl_xor(sm, s, 64);
    const float inv = 1.0f / sm;
    float* prow = attn0 + (size_t)(h * NPATCH + n0 + r) * NPATCH;
#pragma unroll
    for (int j = 0; j < 25; ++j) prow[j * 64 + m_lane] = va[j] * inv;
  }

  // --- biased softmax + prune + renorm, in registers; attn_p -> sfull ---
#pragma unroll
  for (int rr = 0; rr < 2; ++rr) {
    const int r = rA + rr;
    const int n = n0 + r;
    const int nh = n / 40, nw = n % 40;
    const float thr = rr ? thrB : thrA;
    float* srow = sfull + r * SROW;
    float vb[25];
#pragma unroll
    for (int j = 0; j < 25; ++j) {
      const int m = j * 64 + m_lane;
      const int mh = m / 40, mw = m - mh * 40;
      const int dh = nh - mh, dw = nw - mw;
      const float fdh = (float)dh * 0.025f;
      const float fdwa = (float)dw * 0.025f;
      const float fdwb = (float)dw * (1.0f / 96.0f);
      const float dis = fdh * fdh + fdwa * fdwa + fdwb * fdwb;
      const float bias = tprod[h * TBL + (dh + 39) * 79 + (dw + 39)];
      vb[j] = srow[m] + bias + 0.01f * __expf(-fac * dis);
    }
    float mx = -3.4e38f;
#pragma unroll
    for (int j = 0; j < 25; ++j) mx = fmaxf(mx, vb[j]);
#pragma unroll
    for (int s = 32; s; s >>= 1) mx = fmaxf(mx, __shfl_xor(mx, s, 64));
    float sm = 0.f, mn = 3.4e38f;
#pragma unroll
    for (int j = 0; j < 25; ++j) {
      vb[j] = __expf(vb[j] - mx);
      sm += vb[j];
      mn = fminf(mn, vb[j]);
    }
#pragma unroll
    for (int s = 32; s; s >>= 1) {
      sm += __shfl_xor(sm, s, 64);
      mn = fminf(mn, __shfl_xor(mn, s, 64));
    }
    // attn > thresh  <=>  e > mn + thr*(1 - mn)   (everything /sm)
    const float T = mn + thr * (1.0f - mn);
    float ld = 0.f;
#pragma unroll
    for (int j = 0; j < 25; ++j) { if (vb[j] > T) ld += vb[j]; }
#pragma unroll
    for (int s = 32; s; s >>= 1) ld += __shfl_xor(ld, s, 64);
    const float sc = 1.0f / (ld + 1e-6f * sm);     // folded /(deno+1e-6)
#pragma unroll
    for (int j = 0; j < 25; ++j)
      srow[j * 64 + m_lane] = (vb[j] > T) ? vb[j] * sc : 0.f;
  }
  __syncthreads();   // attn_p visible to all waves

  // --- PV: out0[r][d] = sum_m attn_p[r][m] * V[m][d] ---
  const int d = t & 63;
  const int g = t >> 6;
  float acc[8] = {0.f, 0.f, 0.f, 0.f, 0.f, 0.f, 0.f, 0.f};
  const float* vcol = qkv + 2 * DMODEL + h * DHEAD + d;
  const float4* sf4 = reinterpret_cast<const float4*>(sfull);
  for (int m = g * 400; m < g * 400 + 400; m += 4) {
    const float v0 = vcol[(size_t)(m + 0) * QKVLD];
    const float v1 = vcol[(size_t)(m + 1) * QKVLD];
    const float v2 = vcol[(size_t)(m + 2) * QKVLD];
    const float v3 = vcol[(size_t)(m + 3) * QKVLD];
#pragma unroll
    for (int r = 0; r < 8; ++r) {
      const float4 ap = sf4[r * 402 + (m >> 2)];
      acc[r] = fmaf(ap.x, v0, acc[r]);
      acc[r] = fmaf(ap.y, v1, acc[r]);
      acc[r] = fmaf(ap.z, v2, acc[r]);
      acc[r] = fmaf(ap.w, v3, acc[r]);
    }
  }
  float* part = ks;  // [4][8][64]
#pragma unroll
  for (int r = 0; r < 8; ++r) part[(g * 8 + r) * 64 + d] = acc[r];
  __syncthreads();
#pragma unroll
  for (int rep = 0; rep < 2; ++rep) {
    const int e = t + rep * 256;
    const int r = e >> 6, dd = e & 63;
    const float s = part[(0 + r) * 64 + dd] + part[(8 + r) * 64 + dd] +
                    part[(16 + r) * 64 + dd] + part[(24 + r) * 64 + dd];
    out0[(size_t)(n0 + r) * DMODEL + h * DHEAD + dd] = s;
  }
}

extern "C" void kernel_launch(void* const* d_in, const int* in_sizes, int n_in,
                              void* d_out, int out_size, void* d_ws, size_t ws_size,
                              hipStream_t stream) {
  const float* x        = (const float*)d_in[0];
  const float* prob     = (const float*)d_in[1];
  const float* w_qkv    = (const float*)d_in[2];
  const float* table1   = (const float*)d_in[3];
  const float* table2   = (const float*)d_in[4];
  const float* headsita = (const float*)d_in[5];
  const float* w_thresh = (const float*)d_in[6];
  const float* w_out    = (const float*)d_in[7];
  const float* b_out    = (const float*)d_in[8];

  float* out   = (float*)d_out;
  float* attn0 = out + (size_t)NPATCH * DMODEL;

  float* qkvb  = (float*)d_ws;                          // [1600][1536]
  float* out0b = qkvb + (size_t)NPATCH * QKVLD;         // [1600][512]
  float* tpb   = out0b + (size_t)NPATCH * DMODEL;       // [8][6241]

  k_gemm_qkv<<<dim3(25, 24), 256, 0, stream>>>(x, w_qkv, qkvb, QKVLD);
  k_tprod<<<dim3((NHEAD * TBL + 255) / 256), 256, 0, stream>>>(table1, table2, tpb);
  k_attn<<<dim3(200, NHEAD), 256, 0, stream>>>(qkvb, tpb, headsita, w_thresh, attn0, out0b);
  k_gemm_out<<<dim3(25, 8), 256, 0, stream>>>(out0b, w_out, b_out, prob, out);
}

// Round 8
// 378.290 us; speedup vs baseline: 1.7595x; 1.1175x over previous
//
#include <hip/hip_runtime.h>
#include <hip/hip_fp16.h>

#define NPATCH 1600
#define NHEAD 8
#define DHEAD 64
#define DMODEL 512
#define TBL 6241      // 79*79
#define QKVLD 1536
#define KSLD 65       // padded K-tile row stride in float4 (write 2-way, read linear)
#define PHROW 1608    // attn_p fp16 row stride (halfs): 3216B, 16B-aligned rows

// ---------------------------------------------------------------------------
// GEMM: C[M][Nout] = A[M][512] @ W[Nout][512]^T
// ---------------------------------------------------------------------------
__global__ __launch_bounds__(256) void k_gemm_qkv(const float* __restrict__ x,
                                                  const float* __restrict__ w,
                                                  float* __restrict__ c,
                                                  int ldc) {
  __shared__ float As[16][68];
  __shared__ float Bs[16][68];
  const int t = threadIdx.x;
  const int m0 = blockIdx.x * 64;
  const int n0 = blockIdx.y * 64;
  const int tx = t & 15;
  const int ty = t >> 4;
  const int mr = t >> 2;
  const int k4 = (t & 3) * 4;
  float acc[4][4] = {};
  for (int k0 = 0; k0 < DMODEL; k0 += 16) {
    float4 a4 = *reinterpret_cast<const float4*>(x + (size_t)(m0 + mr) * DMODEL + k0 + k4);
    float4 b4 = *reinterpret_cast<const float4*>(w + (size_t)(n0 + mr) * DMODEL + k0 + k4);
    As[k4 + 0][mr] = a4.x; As[k4 + 1][mr] = a4.y; As[k4 + 2][mr] = a4.z; As[k4 + 3][mr] = a4.w;
    Bs[k4 + 0][mr] = b4.x; Bs[k4 + 1][mr] = b4.y; Bs[k4 + 2][mr] = b4.z; Bs[k4 + 3][mr] = b4.w;
    __syncthreads();
    const float4* As4 = reinterpret_cast<const float4*>(&As[0][0]);
    const float4* Bs4 = reinterpret_cast<const float4*>(&Bs[0][0]);
#pragma unroll
    for (int kk = 0; kk < 16; ++kk) {
      float4 av = As4[kk * 17 + tx];
      float4 bv = Bs4[kk * 17 + ty];
      acc[0][0] += av.x * bv.x; acc[0][1] += av.x * bv.y; acc[0][2] += av.x * bv.z; acc[0][3] += av.x * bv.w;
      acc[1][0] += av.y * bv.x; acc[1][1] += av.y * bv.y; acc[1][2] += av.y * bv.z; acc[1][3] += av.y * bv.w;
      acc[2][0] += av.z * bv.x; acc[2][1] += av.z * bv.y; acc[2][2] += av.z * bv.z; acc[2][3] += av.z * bv.w;
      acc[3][0] += av.w * bv.x; acc[3][1] += av.w * bv.y; acc[3][2] += av.w * bv.z; acc[3][3] += av.w * bv.w;
    }
    __syncthreads();
  }
#pragma unroll
  for (int i = 0; i < 4; ++i) {
    float4 o;
    o.x = acc[i][0]; o.y = acc[i][1]; o.z = acc[i][2]; o.w = acc[i][3];
    *reinterpret_cast<float4*>(c + (size_t)(m0 + tx * 4 + i) * ldc + n0 + ty * 4) = o;
  }
}

__global__ __launch_bounds__(256) void k_gemm_out(const float* __restrict__ a,
                                                  const float* __restrict__ w,
                                                  const float* __restrict__ bias,
                                                  const float* __restrict__ prob,
                                                  float* __restrict__ outp) {
  __shared__ float As[16][68];
  __shared__ float Bs[16][68];
  const int t = threadIdx.x;
  const int m0 = blockIdx.x * 64;
  const int n0 = blockIdx.y * 64;
  const int tx = t & 15;
  const int ty = t >> 4;
  const int mr = t >> 2;
  const int k4 = (t & 3) * 4;
  float acc[4][4] = {};
  for (int k0 = 0; k0 < DMODEL; k0 += 16) {
    float4 a4 = *reinterpret_cast<const float4*>(a + (size_t)(m0 + mr) * DMODEL + k0 + k4);
    float4 b4 = *reinterpret_cast<const float4*>(w + (size_t)(n0 + mr) * DMODEL + k0 + k4);
    As[k4 + 0][mr] = a4.x; As[k4 + 1][mr] = a4.y; As[k4 + 2][mr] = a4.z; As[k4 + 3][mr] = a4.w;
    Bs[k4 + 0][mr] = b4.x; Bs[k4 + 1][mr] = b4.y; Bs[k4 + 2][mr] = b4.z; Bs[k4 + 3][mr] = b4.w;
    __syncthreads();
    const float4* As4 = reinterpret_cast<const float4*>(&As[0][0]);
    const float4* Bs4 = reinterpret_cast<const float4*>(&Bs[0][0]);
#pragma unroll
    for (int kk = 0; kk < 16; ++kk) {
      float4 av = As4[kk * 17 + tx];
      float4 bv = Bs4[kk * 17 + ty];
      acc[0][0] += av.x * bv.x; acc[0][1] += av.x * bv.y; acc[0][2] += av.x * bv.z; acc[0][3] += av.x * bv.w;
      acc[1][0] += av.y * bv.x; acc[1][1] += av.y * bv.y; acc[1][2] += av.y * bv.z; acc[1][3] += av.y * bv.w;
      acc[2][0] += av.z * bv.x; acc[2][1] += av.z * bv.y; acc[2][2] += av.z * bv.z; acc[2][3] += av.z * bv.w;
      acc[3][0] += av.w * bv.x; acc[3][1] += av.w * bv.y; acc[3][2] += av.w * bv.z; acc[3][3] += av.w * bv.w;
    }
    __syncthreads();
  }
#pragma unroll
  for (int i = 0; i < 4; ++i) {
    const int row = m0 + tx * 4 + i;
    const bool sel = prob[row] < 0.9f;
    float4 o;
    o.x = acc[i][0] + bias[n0 + ty * 4 + 0];
    o.y = acc[i][1] + bias[n0 + ty * 4 + 1];
    o.z = acc[i][2] + bias[n0 + ty * 4 + 2];
    o.w = acc[i][3] + bias[n0 + ty * 4 + 3];
    if (!sel) { o.x = 0.f; o.y = 0.f; o.z = 0.f; o.w = 0.f; }
    *reinterpret_cast<float4*>(outp + (size_t)row * DMODEL + n0 + ty * 4) = o;
  }
}

__global__ void k_tprod(const float* __restrict__ t1, const float* __restrict__ t2,
                        float* __restrict__ tp) {
  const int o = blockIdx.x * 256 + threadIdx.x;
  if (o < NHEAD * TBL) {
    const int h = o / TBL;
    const int i = o - h * TBL;
    tp[o] = t1[i * NHEAD + h] * t2[i * NHEAD + h];
  }
}

// ---------------------------------------------------------------------------
// Fused attention. One block = (head, 8 query rows), 256 threads, 4 waves.
// R8: raw scores live in REGISTERS ra0/ra1[25] (chunk loop fully unrolled);
// attn_p transported to PV via fp16 LDS (ph). LDS 70.4->44.5 KB => 3 blocks/CU
// (12 waves/CU, 3/SIMD). __launch_bounds__(256,3) caps VGPR at ~168.
// Prune COMPARISON stays fp32 (exact); only post-threshold attn_p is rounded
// to fp16 for the PV multiply (est. |err| ~1e-5 on out).
// ---------------------------------------------------------------------------
__global__ __launch_bounds__(256, 3) void k_attn(const float* __restrict__ qkv,
                                                 const float* __restrict__ tprod,
                                                 const float* __restrict__ headsita,
                                                 const float* __restrict__ w_thresh,
                                                 float* __restrict__ attn0,
                                                 float* __restrict__ out0) {
  __shared__ float ks[16 * KSLD * 4];   // padded K chunk; reused as PV partials (16.6 KB)
  __shared__ float qs[8 * 68];          // Q rows, float4 row stride 17 (2.2 KB)
  __shared__ _Float16 ph[8 * PHROW];    // attn_p fp16 (25.7 KB)
  const int t = threadIdx.x;
  const int h = blockIdx.y;
  const int n0 = blockIdx.x * 8;

  // --- stage Q ---
#pragma unroll
  for (int rep = 0; rep < 2; ++rep) {
    const int e = t + rep * 256;
    const int r = e >> 6, dd = e & 63;
    qs[r * 68 + dd] = qkv[(size_t)(n0 + r) * QKVLD + h * DHEAD + dd];
  }
  __syncthreads();

  const int m_lane = t & 63;
  const int wv = t >> 6;
  const int rA = wv * 2, rB = rA + 1;

  // --- per-row threshold factor (64-lane reduce) ---
  float thrA, thrB;
  {
    const float wt = w_thresh[m_lane];
    float pA = qs[rA * 68 + m_lane] * wt;
    float pB = qs[rB * 68 + m_lane] * wt;
#pragma unroll
    for (int s = 32; s; s >>= 1) {
      pA += __shfl_xor(pA, s, 64);
      pB += __shfl_xor(pB, s, 64);
    }
    thrA = (1.0f / (1.0f + __expf(-pA))) * 0.11920292202211755f;  // sigmoid(p)*sigmoid(-2)
    thrB = (1.0f / (1.0f + __expf(-pB))) * 0.11920292202211755f;
  }
  const float hs = headsita[h];
  const float fac = 1.0f / (2.0f * hs * hs + 1e-6f);

  // --- QK^T over 25 chunks of 64 keys -> raw scores in registers ---
  float ra0[25], ra1[25];
  float4* ks4 = reinterpret_cast<float4*>(ks);
  const float4* qs4 = reinterpret_cast<const float4*>(qs);
  const int c4 = t & 15;                 // staging d-quad
  const int krb = t >> 4;                // staging key 0..15
  const float* gK = qkv + DMODEL + h * DHEAD + c4 * 4;

#pragma unroll
  for (int mc = 0; mc < 25; ++mc) {
    const int mb = mc * 64;
    float4 s0v = *reinterpret_cast<const float4*>(gK + (size_t)(mb + krb) * QKVLD);
    float4 s1v = *reinterpret_cast<const float4*>(gK + (size_t)(mb + krb + 16) * QKVLD);
    float4 s2v = *reinterpret_cast<const float4*>(gK + (size_t)(mb + krb + 32) * QKVLD);
    float4 s3v = *reinterpret_cast<const float4*>(gK + (size_t)(mb + krb + 48) * QKVLD);
    __syncthreads();                      // previous chunk fully consumed
    ks4[c4 * KSLD + krb]      = s0v;
    ks4[c4 * KSLD + krb + 16] = s1v;
    ks4[c4 * KSLD + krb + 32] = s2v;
    ks4[c4 * KSLD + krb + 48] = s3v;
    __syncthreads();                      // chunk ready

    float acc0 = 0.f, acc1 = 0.f;
#pragma unroll
    for (int d4 = 0; d4 < 16; ++d4) {
      const float4 kv = ks4[d4 * KSLD + m_lane];
      const float4 qa = qs4[rA * 17 + d4];
      const float4 qb = qs4[rB * 17 + d4];
      acc0 = fmaf(kv.x, qa.x, acc0); acc0 = fmaf(kv.y, qa.y, acc0);
      acc0 = fmaf(kv.z, qa.z, acc0); acc0 = fmaf(kv.w, qa.w, acc0);
      acc1 = fmaf(kv.x, qb.x, acc1); acc1 = fmaf(kv.y, qb.y, acc1);
      acc1 = fmaf(kv.z, qb.z, acc1); acc1 = fmaf(kv.w, qb.w, acc1);
    }
    ra0[mc] = acc0 * 0.125f;
    ra1[mc] = acc1 * 0.125f;
  }

  // --- attn0 = softmax(raw): pure register/shuffle, written once, coalesced.
  //     exp recomputed for the store (identical inputs -> identical values). ---
#define ATTN0_ROW(RA, ROW)                                                      \
  {                                                                             \
    float mx = -3.4e38f;                                                        \
    _Pragma("unroll") for (int j = 0; j < 25; ++j) mx = fmaxf(mx, RA[j]);       \
    _Pragma("unroll") for (int s = 32; s; s >>= 1) mx = fmaxf(mx, __shfl_xor(mx, s, 64)); \
    float sm = 0.f;                                                             \
    _Pragma("unroll") for (int j = 0; j < 25; ++j) sm += __expf(RA[j] - mx);    \
    _Pragma("unroll") for (int s = 32; s; s >>= 1) sm += __shfl_xor(sm, s, 64); \
    const float inv = 1.0f / sm;                                                \
    float* prow = attn0 + (size_t)(h * NPATCH + n0 + (ROW)) * NPATCH;           \
    _Pragma("unroll") for (int j = 0; j < 25; ++j)                              \
      prow[j * 64 + m_lane] = __expf(RA[j] - mx) * inv;                         \
  }
  ATTN0_ROW(ra0, rA)
  ATTN0_ROW(ra1, rB)
#undef ATTN0_ROW

  // --- biased softmax + prune + renorm, in registers; attn_p -> ph (fp16) ---
#define PRUNE_ROW(RA, ROW, THR)                                                 \
  {                                                                             \
    const int n = n0 + (ROW);                                                   \
    const int nh = n / 40, nw = n % 40;                                         \
    _Pragma("unroll") for (int j = 0; j < 25; ++j) {                            \
      const int m = j * 64 + m_lane;                                            \
      const int mh = m / 40, mw = m - mh * 40;                                  \
      const int dh = nh - mh, dw = nw - mw;                                     \
      const float fdh = (float)dh * 0.025f;                                     \
      const float fdwa = (float)dw * 0.025f;                                    \
      const float fdwb = (float)dw * (1.0f / 96.0f);                            \
      const float dis = fdh * fdh + fdwa * fdwa + fdwb * fdwb;                  \
      const float bias = tprod[h * TBL + (dh + 39) * 79 + (dw + 39)];           \
      RA[j] = RA[j] + bias + 0.01f * __expf(-fac * dis);                        \
    }                                                                           \
    float mx = -3.4e38f;                                                        \
    _Pragma("unroll") for (int j = 0; j < 25; ++j) mx = fmaxf(mx, RA[j]);       \
    _Pragma("unroll") for (int s = 32; s; s >>= 1) mx = fmaxf(mx, __shfl_xor(mx, s, 64)); \
    float sm = 0.f, mn = 3.4e38f;                                               \
    _Pragma("unroll") for (int j = 0; j < 25; ++j) {                            \
      RA[j] = __expf(RA[j] - mx);                                               \
      sm += RA[j];                                                              \
      mn = fminf(mn, RA[j]);                                                    \
    }                                                                           \
    _Pragma("unroll") for (int s = 32; s; s >>= 1) {                            \
      sm += __shfl_xor(sm, s, 64);                                              \
      mn = fminf(mn, __shfl_xor(mn, s, 64));                                    \
    }                                                                           \
    const float T = mn + (THR) * (1.0f - mn);                                   \
    float ld = 0.f;                                                             \
    _Pragma("unroll") for (int j = 0; j < 25; ++j) { if (RA[j] > T) ld += RA[j]; } \
    _Pragma("unroll") for (int s = 32; s; s >>= 1) ld += __shfl_xor(ld, s, 64); \
    const float sc = 1.0f / (ld + 1e-6f * sm);                                  \
    _Float16* hrow = ph + (ROW) * PHROW;                                        \
    _Pragma("unroll") for (int j = 0; j < 25; ++j)                              \
      hrow[j * 64 + m_lane] = (_Float16)((RA[j] > T) ? RA[j] * sc : 0.f);       \
  }
  PRUNE_ROW(ra0, rA, thrA)
  PRUNE_ROW(ra1, rB, thrB)
#undef PRUNE_ROW

  __syncthreads();   // attn_p visible to all waves; ks free for reuse

  // --- PV: out0[r][d] = sum_m attn_p[r][m] * V[m][d] (attn_p fp16) ---
  const int d = t & 63;
  const int g = t >> 6;
  float acc[8] = {0.f, 0.f, 0.f, 0.f, 0.f, 0.f, 0.f, 0.f};
  const float* vcol = qkv + 2 * DMODEL + h * DHEAD + d;
  const float4* ph4 = reinterpret_cast<const float4*>(ph);
  for (int m = g * 400; m < g * 400 + 400; m += 8) {
    float v[8];
#pragma unroll
    for (int i = 0; i < 8; ++i) v[i] = vcol[(size_t)(m + i) * QKVLD];
#pragma unroll
    for (int r = 0; r < 8; ++r) {
      const float4 raw = ph4[(r * PHROW + m) >> 3];   // 8 halves, wave-uniform broadcast
      const _Float16* hp = reinterpret_cast<const _Float16*>(&raw);
#pragma unroll
      for (int i = 0; i < 8; ++i) acc[r] = fmaf((float)hp[i], v[i], acc[r]);
    }
  }
  float* part = ks;  // [4][8][64]
#pragma unroll
  for (int r = 0; r < 8; ++r) part[(g * 8 + r) * 64 + d] = acc[r];
  __syncthreads();
#pragma unroll
  for (int rep = 0; rep < 2; ++rep) {
    const int e = t + rep * 256;
    const int r = e >> 6, dd = e & 63;
    const float s = part[(0 + r) * 64 + dd] + part[(8 + r) * 64 + dd] +
                    part[(16 + r) * 64 + dd] + part[(24 + r) * 64 + dd];
    out0[(size_t)(n0 + r) * DMODEL + h * DHEAD + dd] = s;
  }
}

extern "C" void kernel_launch(void* const* d_in, const int* in_sizes, int n_in,
                              void* d_out, int out_size, void* d_ws, size_t ws_size,
                              hipStream_t stream) {
  const float* x        = (const float*)d_in[0];
  const float* prob     = (const float*)d_in[1];
  const float* w_qkv    = (const float*)d_in[2];
  const float* table1   = (const float*)d_in[3];
  const float* table2   = (const float*)d_in[4];
  const float* headsita = (const float*)d_in[5];
  const float* w_thresh = (const float*)d_in[6];
  const float* w_out    = (const float*)d_in[7];
  const float* b_out    = (const float*)d_in[8];

  float* out   = (float*)d_out;
  float* attn0 = out + (size_t)NPATCH * DMODEL;

  float* qkvb  = (float*)d_ws;                          // [1600][1536]
  float* out0b = qkvb + (size_t)NPATCH * QKVLD;         // [1600][512]
  float* tpb   = out0b + (size_t)NPATCH * DMODEL;       // [8][6241]

  k_gemm_qkv<<<dim3(25, 24), 256, 0, stream>>>(x, w_qkv, qkvb, QKVLD);
  k_tprod<<<dim3((NHEAD * TBL + 255) / 256), 256, 0, stream>>>(table1, table2, tpb);
  k_attn<<<dim3(200, NHEAD), 256, 0, stream>>>(qkvb, tpb, headsita, w_thresh, attn0, out0b);
  k_gemm_out<<<dim3(25, 8), 256, 0, stream>>>(out0b, w_out, b_out, prob, out);
}